// Round 7
// baseline (77.000 us; speedup 1.0000x reference)
//
#include <hip/hip_runtime.h>
#include <hip/hip_bf16.h>

#define BB 2
#define SS 1024
#define DD 256
#define NCH 4           // k-chunks in attn
#define KCH 256         // k-chunk size

typedef __attribute__((ext_vector_type(8))) short bf16x8;
typedef __attribute__((ext_vector_type(4))) float f32x4;

__device__ __forceinline__ unsigned short f2bf(float f) {
    __hip_bfloat16 h = __float2bfloat16(f);
    return *reinterpret_cast<unsigned short*>(&h);
}
__device__ __forceinline__ float bf2f(unsigned short u) {
    __hip_bfloat16 h;
    *reinterpret_cast<unsigned short*>(&h) = u;
    return __bfloat162float(h);
}

// ---------------------------------------------------------------------------
// Kernel 1: QKV projection via MFMA (byte-identical to round 6).
// ---------------------------------------------------------------------------
__global__ __launch_bounds__(256, 2) void qkv_mfma(
    const float* __restrict__ x,
    const float* __restrict__ Wq, const float* __restrict__ bq,
    const float* __restrict__ Wk, const float* __restrict__ bk,
    const float* __restrict__ Wv, const float* __restrict__ bv,
    unsigned short* __restrict__ Qb, unsigned short* __restrict__ Kb,
    unsigned short* __restrict__ VB,
    float* __restrict__ qq, float* __restrict__ kk)
{
    __shared__ float red[4][16];
    const int t = threadIdx.x;
    const int w = t >> 6, l = t & 63, lr = l & 15, lc = l >> 4;
    const int mat = blockIdx.x % 3;
    const int tile = blockIdx.x / 3;
    const int r0 = tile * 16;                 // global seq row (incl. batch)
    const int b = r0 >> 10;
    const int s_in_base = r0 & (SS - 1);

    const float* W    = (mat == 0) ? Wq : (mat == 1) ? Wk : Wv;
    const float* bias = (mat == 0) ? bq : (mat == 1) ? bk : bv;

    // A-frags from x, all 8 d-blocks (reused by 4 col-blocks)
    bf16x8 af[8];
#pragma unroll
    for (int db = 0; db < 8; ++db) {
        const float* xp = x + (size_t)(r0 + lr) * DD + db * 32 + 8 * lc;
        float4 f0 = *(const float4*)(xp);
        float4 f1 = *(const float4*)(xp + 4);
        bf16x8 a;
        a[0] = (short)f2bf(f0.x); a[1] = (short)f2bf(f0.y);
        a[2] = (short)f2bf(f0.z); a[3] = (short)f2bf(f0.w);
        a[4] = (short)f2bf(f1.x); a[5] = (short)f2bf(f1.y);
        a[6] = (short)f2bf(f1.z); a[7] = (short)f2bf(f1.w);
        af[db] = a;
    }

    float nrm[4] = {0.f, 0.f, 0.f, 0.f};

#pragma unroll
    for (int cb = 0; cb < 4; ++cb) {
        const int jb = 64 * w + 16 * cb;
        f32x4 acc = {0.f, 0.f, 0.f, 0.f};
#pragma unroll
        for (int db = 0; db < 8; ++db) {
            const float* wp = W + (size_t)(jb + lr) * DD + db * 32 + 8 * lc;
            float4 f0 = *(const float4*)(wp);
            float4 f1 = *(const float4*)(wp + 4);
            bf16x8 bf;
            bf[0] = (short)f2bf(f0.x); bf[1] = (short)f2bf(f0.y);
            bf[2] = (short)f2bf(f0.z); bf[3] = (short)f2bf(f0.w);
            bf[4] = (short)f2bf(f1.x); bf[5] = (short)f2bf(f1.y);
            bf[6] = (short)f2bf(f1.z); bf[7] = (short)f2bf(f1.w);
            acc = __builtin_amdgcn_mfma_f32_16x16x32_bf16(af[db], bf, acc, 0, 0, 0);
        }
        const float bv_ = bias[jb + lr];
#pragma unroll
        for (int r = 0; r < 4; ++r) {
            const int srow = r0 + lc * 4 + r;     // C/D: row=(l>>4)*4+r, col=l%16
            const float v = acc[r] + bv_;
            const unsigned short h = f2bf(v);
            if (mat == 0) {
                Qb[(size_t)srow * DD + jb + lr] = h;
                const float hv = bf2f(h); nrm[r] += hv * hv;
            } else if (mat == 1) {
                Kb[(size_t)srow * DD + jb + lr] = h;
                const float hv = bf2f(h); nrm[r] += hv * hv;
            } else {
                // VB layout: tile(b, kb32=s/32, db16=d/16) of 1024B;
                // lane (kslot*16 + d%16) holds 8 bf16 for k=kb32*32+kslot*8+jj
                const int s_in = s_in_base + lc * 4 + r;
                const int kb32 = s_in >> 5;
                const int kslot = (s_in >> 3) & 3;
                const int jj = s_in & 7;
                const int db16 = 4 * w + cb;
                const size_t off = ((size_t)((b * 32 + kb32) * 16 + db16) << 9)
                                 + ((kslot * 16 + lr) << 3) + jj;
                VB[off] = h;
            }
        }
    }

    if (mat < 2) {
#pragma unroll
        for (int r = 0; r < 4; ++r) {
            float n = nrm[r];
#pragma unroll
            for (int m = 1; m < 16; m <<= 1) n += __shfl_xor(n, m, 64);
            if (lr == 0) red[w][lc * 4 + r] = n;
        }
        __syncthreads();
        if (t < 16) {
            const float s = red[0][t] + red[1][t] + red[2][t] + red[3][t];
            if (mat == 0) qq[r0 + t] = s;
            else          kk[r0 + t] = s;
        }
    }
}

// ---------------------------------------------------------------------------
// Kernel 2: partial attention via MFMA (byte-identical to round 6).
// Launched TWICE this round for time attribution (idempotent: pure function
// of Qb/Kb/VB -> Opart/esum; stream order serializes the two launches).
// ---------------------------------------------------------------------------
__global__ __launch_bounds__(256, 2) void attn_part_mfma(
    const unsigned short* __restrict__ Qb, const unsigned short* __restrict__ Kb,
    const unsigned short* __restrict__ VB,
    const float* __restrict__ qq, const float* __restrict__ kk,
    float* __restrict__ Opart, float* __restrict__ esum)
{
    __shared__ unsigned short P_s[16 * 256];   // 8 KB, XOR-swizzled
    __shared__ float kk_s[KCH];
    __shared__ float qq_s[16];
    __shared__ float es_red[4][16];

    const int t = threadIdx.x;
    const int w = t >> 6, l = t & 63, lr = l & 15, lc = l >> 4;
    const int qtile = blockIdx.x >> 2;
    const int c = blockIdx.x & 3;
    const int rowbase = qtile * 16;            // global row
    const int b = rowbase >> 10;
    const int s0 = c * KCH;                    // chunk start within batch

    kk_s[t] = kk[b * SS + s0 + t];
    if (t < 16) qq_s[t] = qq[rowbase + t];

    // Q A-frags: lane(row=l%16, 8 contiguous d), held in regs for the block
    bf16x8 qf[8];
#pragma unroll
    for (int db = 0; db < 8; ++db)
        qf[db] = *(const bf16x8*)(Qb + (size_t)(rowbase + lr) * DD + db * 32 + 8 * lc);

    __syncthreads();

    // ---- QK^T + exp ----
    float psum[4] = {0.f, 0.f, 0.f, 0.f};
#pragma unroll
    for (int kbi = 0; kbi < 4; ++kbi) {
        const int kb = 64 * w + 16 * kbi;
        f32x4 acc = {0.f, 0.f, 0.f, 0.f};
#pragma unroll
        for (int db = 0; db < 8; ++db) {
            bf16x8 kf = *(const bf16x8*)(
                Kb + (size_t)(b * SS + s0 + kb + lr) * DD + db * 32 + 8 * lc);
            acc = __builtin_amdgcn_mfma_f32_16x16x32_bf16(qf[db], kf, acc, 0, 0, 0);
        }
        const int kcol = kb + lr;
        const float kkv = kk_s[kcol];
#pragma unroll
        for (int r = 0; r < 4; ++r) {
            const int qi = lc * 4 + r;
            const float d2 = fmaxf(qq_s[qi] + kkv - 2.f * acc[r], 0.f);
            const float e = __expf(-sqrtf(d2) * 0.0625f);
            psum[r] += e;
            P_s[qi * 256 + (kcol ^ ((qi & 7) << 3))] = f2bf(e);
        }
    }
    // per-row e-sums: reduce across l%16, then across waves via LDS
#pragma unroll
    for (int r = 0; r < 4; ++r) {
        float s = psum[r];
#pragma unroll
        for (int m = 1; m < 16; m <<= 1) s += __shfl_xor(s, m, 64);
        if (lr == 0) es_red[w][lc * 4 + r] = s;
    }
    __syncthreads();
    if (t < 16)
        esum[(size_t)c * (BB * SS) + rowbase + t] =
            es_red[0][t] + es_red[1][t] + es_red[2][t] + es_red[3][t];

    // ---- PV ----
    f32x4 acc2[4];
#pragma unroll
    for (int i = 0; i < 4; ++i) acc2[i] = (f32x4){0.f, 0.f, 0.f, 0.f};

#pragma unroll
    for (int ki = 0; ki < 8; ++ki) {
        // A = P: lane(row q=l%16, k = 32ki + 8*(l>>4) + j), swizzled read
        bf16x8 pf = *(const bf16x8*)(
            P_s + lr * 256 + ((32 * ki + 8 * lc) ^ ((lr & 7) << 3)));
        const size_t tbase =
            ((size_t)((b * 32 + c * 8 + ki) * 16 + 4 * w) << 9) + l * 8;
#pragma unroll
        for (int dbi = 0; dbi < 4; ++dbi) {
            bf16x8 vf = *(const bf16x8*)(VB + tbase + ((size_t)dbi << 9));
            acc2[dbi] = __builtin_amdgcn_mfma_f32_16x16x32_bf16(pf, vf, acc2[dbi], 0, 0, 0);
        }
    }
#pragma unroll
    for (int dbi = 0; dbi < 4; ++dbi)
#pragma unroll
        for (int r = 0; r < 4; ++r)
            Opart[((size_t)c * (BB * SS) + rowbase + lc * 4 + r) * DD
                  + 64 * w + 16 * dbi + lr] = acc2[dbi][r];
}

// ---------------------------------------------------------------------------
// Kernel 3: combine + output projection via MFMA (byte-identical to round 6).
// ---------------------------------------------------------------------------
__global__ __launch_bounds__(256, 2) void combine_mfma(
    const float* __restrict__ Opart, const float* __restrict__ esum,
    const float* __restrict__ Wo, const float* __restrict__ bo,
    float* __restrict__ out)
{
    __shared__ float inv_s[16];
    const int t = threadIdx.x;
    const int w = t >> 6, l = t & 63, lr = l & 15, lc = l >> 4;
    const int r0 = (blockIdx.x >> 2) * 16;   // global row
    const int ch = blockIdx.x & 3;           // col quarter

    if (t < 16) {
        float d = 0.f;
#pragma unroll
        for (int c = 0; c < NCH; ++c) d += esum[(size_t)c * (BB * SS) + r0 + t];
        inv_s[t] = 1.f / d;
    }
    __syncthreads();

    const float inv = inv_s[lr];
    bf16x8 af[8];
#pragma unroll
    for (int db = 0; db < 8; ++db) {
        const float* op = Opart + (size_t)(r0 + lr) * DD + db * 32 + 8 * lc;
        float s0 = 0.f, s1 = 0.f, s2 = 0.f, s3 = 0.f;
        float s4 = 0.f, s5 = 0.f, s6 = 0.f, s7 = 0.f;
#pragma unroll
        for (int c = 0; c < NCH; ++c) {
            const float* p = op + (size_t)c * ((size_t)BB * SS * DD);
            float4 a0 = *(const float4*)(p);
            float4 a1 = *(const float4*)(p + 4);
            s0 += a0.x; s1 += a0.y; s2 += a0.z; s3 += a0.w;
            s4 += a1.x; s5 += a1.y; s6 += a1.z; s7 += a1.w;
        }
        bf16x8 a;
        a[0] = (short)f2bf(s0 * inv); a[1] = (short)f2bf(s1 * inv);
        a[2] = (short)f2bf(s2 * inv); a[3] = (short)f2bf(s3 * inv);
        a[4] = (short)f2bf(s4 * inv); a[5] = (short)f2bf(s5 * inv);
        a[6] = (short)f2bf(s6 * inv); a[7] = (short)f2bf(s7 * inv);
        af[db] = a;
    }

    const int jb = 64 * ch + 16 * w;
    f32x4 acc = {0.f, 0.f, 0.f, 0.f};
#pragma unroll
    for (int db = 0; db < 8; ++db) {
        const float* wp = Wo + (size_t)(jb + lr) * DD + db * 32 + 8 * lc;
        float4 f0 = *(const float4*)(wp);
        float4 f1 = *(const float4*)(wp + 4);
        bf16x8 bf;
        bf[0] = (short)f2bf(f0.x); bf[1] = (short)f2bf(f0.y);
        bf[2] = (short)f2bf(f0.z); bf[3] = (short)f2bf(f0.w);
        bf[4] = (short)f2bf(f1.x); bf[5] = (short)f2bf(f1.y);
        bf[6] = (short)f2bf(f1.z); bf[7] = (short)f2bf(f1.w);
        acc = __builtin_amdgcn_mfma_f32_16x16x32_bf16(af[db], bf, acc, 0, 0, 0);
    }
    const float bov = bo[jb + lr];
#pragma unroll
    for (int r = 0; r < 4; ++r)
        out[(size_t)(r0 + lc * 4 + r) * DD + jb + lr] = acc[r] + bov;
}

// ---------------------------------------------------------------------------
extern "C" void kernel_launch(void* const* d_in, const int* in_sizes, int n_in,
                              void* d_out, int out_size, void* d_ws, size_t ws_size,
                              hipStream_t stream) {
    const float* x  = (const float*)d_in[0];
    const float* Wq = (const float*)d_in[1];
    const float* bq = (const float*)d_in[2];
    const float* Wk = (const float*)d_in[3];
    const float* bk = (const float*)d_in[4];
    const float* Wv = (const float*)d_in[5];
    const float* bv = (const float*)d_in[6];
    const float* Wo = (const float*)d_in[7];
    const float* bo = (const float*)d_in[8];
    float* out = (float*)d_out;

    // ws layout: Qb | Kb | VB (bf16) | qq | kk | esum | Opart (fp32)
    const size_t rows = (size_t)BB * SS;            // 2048
    unsigned short* Qb = (unsigned short*)d_ws;
    unsigned short* Kb = Qb + rows * DD;
    unsigned short* VB = Kb + rows * DD;
    float* qq    = (float*)(VB + rows * DD);
    float* kk    = qq + rows;
    float* esum  = kk + rows;
    float* Opart = esum + (size_t)NCH * rows;       // NCH*rows*DD floats

    qkv_mfma<<<(int)(rows / 16) * 3, 256, 0, stream>>>(
        x, Wq, bq, Wk, bk, Wv, bv, Qb, Kb, VB, qq, kk);
    // ATTRIBUTION: attn launched twice (idempotent). dur_us - 62.25 = t_attn.
    attn_part_mfma<<<(int)(rows / 16) * NCH, 256, 0, stream>>>(
        Qb, Kb, VB, qq, kk, Opart, esum);
    attn_part_mfma<<<(int)(rows / 16) * NCH, 256, 0, stream>>>(
        Qb, Kb, VB, qq, kk, Opart, esum);
    combine_mfma<<<(int)(rows / 16) * 4, 256, 0, stream>>>(
        Opart, esum, Wo, bo, out);
}

// Round 8
// 57.121 us; speedup vs baseline: 1.3480x; 1.3480x over previous
//
#include <hip/hip_runtime.h>
#include <hip/hip_bf16.h>

#define BB 2
#define SS 1024
#define DD 256
#define NCH 4           // k-chunks in attn
#define KCH 256         // k-chunk size

typedef __attribute__((ext_vector_type(8))) short bf16x8;
typedef __attribute__((ext_vector_type(4))) float f32x4;

__device__ __forceinline__ unsigned short f2bf(float f) {
    __hip_bfloat16 h = __float2bfloat16(f);
    return *reinterpret_cast<unsigned short*>(&h);
}
__device__ __forceinline__ float bf2f(unsigned short u) {
    __hip_bfloat16 h;
    *reinterpret_cast<unsigned short*>(&h) = u;
    return __bfloat162float(h);
}
__device__ __forceinline__ bf16x8 cvt8(float4 f0, float4 f1) {
    bf16x8 o;
    o[0] = (short)f2bf(f0.x); o[1] = (short)f2bf(f0.y);
    o[2] = (short)f2bf(f0.z); o[3] = (short)f2bf(f0.w);
    o[4] = (short)f2bf(f1.x); o[5] = (short)f2bf(f1.y);
    o[6] = (short)f2bf(f1.z); o[7] = (short)f2bf(f1.w);
    return o;
}

// ---------------------------------------------------------------------------
// Kernel 0: one-pass fp32->bf16 conversion of x and all four weights.
// unit = 8 elements (2 float4 loads -> 1 bf16x8 store). 98304 units, 384 blk.
// Removes the 128x-redundant in-loop W conversion that dominated qkv (R7
// attribution: qkv ~40us for 403M MACs vs attn 14.7us for 1074M MACs).
// ---------------------------------------------------------------------------
__global__ __launch_bounds__(256) void cvt_bf16(
    const float* __restrict__ x,
    const float* __restrict__ Wq, const float* __restrict__ Wk,
    const float* __restrict__ Wv, const float* __restrict__ Wo,
    unsigned short* __restrict__ xb,
    unsigned short* __restrict__ Wqb, unsigned short* __restrict__ Wkb,
    unsigned short* __restrict__ Wvb, unsigned short* __restrict__ Wob)
{
    const int u = blockIdx.x * 256 + threadIdx.x;   // unit index
    const float* src;
    unsigned short* dst;
    int base;
    if (u < 65536)      { src = x;  dst = xb;  base = u; }          // 2048*256
    else if (u < 73728) { src = Wq; dst = Wqb; base = u - 65536; }  // 256*256
    else if (u < 81920) { src = Wk; dst = Wkb; base = u - 73728; }
    else if (u < 90112) { src = Wv; dst = Wvb; base = u - 81920; }
    else                { src = Wo; dst = Wob; base = u - 90112; }
    const float4* s4 = (const float4*)src + (size_t)base * 2;
    float4 f0 = s4[0], f1 = s4[1];
    *(bf16x8*)(dst + (size_t)base * 8) = cvt8(f0, f1);
}

// ---------------------------------------------------------------------------
// Kernel 1: QKV projection via MFMA, all-bf16 inputs (no in-loop conversion).
// grid = 128 rowtiles x 3 mats = 384. Block = 16 seq-rows x 256 out-cols.
// Inner loop per cb: 8 x {16B bf16 load -> MFMA}.
// ---------------------------------------------------------------------------
__global__ __launch_bounds__(256, 2) void qkv_mfma(
    const unsigned short* __restrict__ xb,
    const unsigned short* __restrict__ Wqb, const float* __restrict__ bq,
    const unsigned short* __restrict__ Wkb, const float* __restrict__ bk,
    const unsigned short* __restrict__ Wvb, const float* __restrict__ bv,
    unsigned short* __restrict__ Qb, unsigned short* __restrict__ Kb,
    unsigned short* __restrict__ VB,
    float* __restrict__ qq, float* __restrict__ kk)
{
    __shared__ float red[4][16];
    const int t = threadIdx.x;
    const int w = t >> 6, l = t & 63, lr = l & 15, lc = l >> 4;
    const int mat = blockIdx.x % 3;
    const int tile = blockIdx.x / 3;
    const int r0 = tile * 16;                 // global seq row (incl. batch)
    const int b = r0 >> 10;
    const int s_in_base = r0 & (SS - 1);

    const unsigned short* W = (mat == 0) ? Wqb : (mat == 1) ? Wkb : Wvb;
    const float* bias       = (mat == 0) ? bq  : (mat == 1) ? bk  : bv;

    // A-frags from xb: lane(row=l%16, 8 contiguous d), coalesced 16B loads
    bf16x8 af[8];
#pragma unroll
    for (int db = 0; db < 8; ++db)
        af[db] = *(const bf16x8*)(xb + (size_t)(r0 + lr) * DD + db * 32 + 8 * lc);

    float nrm[4] = {0.f, 0.f, 0.f, 0.f};

#pragma unroll
    for (int cb = 0; cb < 4; ++cb) {
        const int jb = 64 * w + 16 * cb;
        f32x4 acc = {0.f, 0.f, 0.f, 0.f};
#pragma unroll
        for (int db = 0; db < 8; ++db) {
            bf16x8 bf = *(const bf16x8*)(W + (size_t)(jb + lr) * DD + db * 32 + 8 * lc);
            acc = __builtin_amdgcn_mfma_f32_16x16x32_bf16(af[db], bf, acc, 0, 0, 0);
        }
        const float bv_ = bias[jb + lr];
#pragma unroll
        for (int r = 0; r < 4; ++r) {
            const int srow = r0 + lc * 4 + r;     // C/D: row=(l>>4)*4+r, col=l%16
            const float v = acc[r] + bv_;
            const unsigned short h = f2bf(v);
            if (mat == 0) {
                Qb[(size_t)srow * DD + jb + lr] = h;
                const float hv = bf2f(h); nrm[r] += hv * hv;
            } else if (mat == 1) {
                Kb[(size_t)srow * DD + jb + lr] = h;
                const float hv = bf2f(h); nrm[r] += hv * hv;
            } else {
                // VB layout: tile(b, kb32=s/32, db16=d/16) of 1024B;
                // lane (kslot*16 + d%16) holds 8 bf16 for k=kb32*32+kslot*8+jj
                const int s_in = s_in_base + lc * 4 + r;
                const int kb32 = s_in >> 5;
                const int kslot = (s_in >> 3) & 3;
                const int jj = s_in & 7;
                const int db16 = 4 * w + cb;
                const size_t off = ((size_t)((b * 32 + kb32) * 16 + db16) << 9)
                                 + ((kslot * 16 + lr) << 3) + jj;
                VB[off] = h;
            }
        }
    }

    if (mat < 2) {
#pragma unroll
        for (int r = 0; r < 4; ++r) {
            float n = nrm[r];
#pragma unroll
            for (int m = 1; m < 16; m <<= 1) n += __shfl_xor(n, m, 64);
            if (lr == 0) red[w][lc * 4 + r] = n;
        }
        __syncthreads();
        if (t < 16) {
            const float s = red[0][t] + red[1][t] + red[2][t] + red[3][t];
            if (mat == 0) qq[r0 + t] = s;
            else          kk[r0 + t] = s;
        }
    }
}

// ---------------------------------------------------------------------------
// Kernel 2: partial attention via MFMA (byte-identical to round 6; single
// launch restored).
// ---------------------------------------------------------------------------
__global__ __launch_bounds__(256, 2) void attn_part_mfma(
    const unsigned short* __restrict__ Qb, const unsigned short* __restrict__ Kb,
    const unsigned short* __restrict__ VB,
    const float* __restrict__ qq, const float* __restrict__ kk,
    float* __restrict__ Opart, float* __restrict__ esum)
{
    __shared__ unsigned short P_s[16 * 256];   // 8 KB, XOR-swizzled
    __shared__ float kk_s[KCH];
    __shared__ float qq_s[16];
    __shared__ float es_red[4][16];

    const int t = threadIdx.x;
    const int w = t >> 6, l = t & 63, lr = l & 15, lc = l >> 4;
    const int qtile = blockIdx.x >> 2;
    const int c = blockIdx.x & 3;
    const int rowbase = qtile * 16;            // global row
    const int b = rowbase >> 10;
    const int s0 = c * KCH;                    // chunk start within batch

    kk_s[t] = kk[b * SS + s0 + t];
    if (t < 16) qq_s[t] = qq[rowbase + t];

    // Q A-frags: lane(row=l%16, 8 contiguous d), held in regs for the block
    bf16x8 qf[8];
#pragma unroll
    for (int db = 0; db < 8; ++db)
        qf[db] = *(const bf16x8*)(Qb + (size_t)(rowbase + lr) * DD + db * 32 + 8 * lc);

    __syncthreads();

    // ---- QK^T + exp ----
    float psum[4] = {0.f, 0.f, 0.f, 0.f};
#pragma unroll
    for (int kbi = 0; kbi < 4; ++kbi) {
        const int kb = 64 * w + 16 * kbi;
        f32x4 acc = {0.f, 0.f, 0.f, 0.f};
#pragma unroll
        for (int db = 0; db < 8; ++db) {
            bf16x8 kf = *(const bf16x8*)(
                Kb + (size_t)(b * SS + s0 + kb + lr) * DD + db * 32 + 8 * lc);
            acc = __builtin_amdgcn_mfma_f32_16x16x32_bf16(qf[db], kf, acc, 0, 0, 0);
        }
        const int kcol = kb + lr;
        const float kkv = kk_s[kcol];
#pragma unroll
        for (int r = 0; r < 4; ++r) {
            const int qi = lc * 4 + r;
            const float d2 = fmaxf(qq_s[qi] + kkv - 2.f * acc[r], 0.f);
            const float e = __expf(-sqrtf(d2) * 0.0625f);
            psum[r] += e;
            P_s[qi * 256 + (kcol ^ ((qi & 7) << 3))] = f2bf(e);
        }
    }
    // per-row e-sums: reduce across l%16, then across waves via LDS
#pragma unroll
    for (int r = 0; r < 4; ++r) {
        float s = psum[r];
#pragma unroll
        for (int m = 1; m < 16; m <<= 1) s += __shfl_xor(s, m, 64);
        if (lr == 0) es_red[w][lc * 4 + r] = s;
    }
    __syncthreads();
    if (t < 16)
        esum[(size_t)c * (BB * SS) + rowbase + t] =
            es_red[0][t] + es_red[1][t] + es_red[2][t] + es_red[3][t];

    // ---- PV ----
    f32x4 acc2[4];
#pragma unroll
    for (int i = 0; i < 4; ++i) acc2[i] = (f32x4){0.f, 0.f, 0.f, 0.f};

#pragma unroll
    for (int ki = 0; ki < 8; ++ki) {
        // A = P: lane(row q=l%16, k = 32ki + 8*(l>>4) + j), swizzled read
        bf16x8 pf = *(const bf16x8*)(
            P_s + lr * 256 + ((32 * ki + 8 * lc) ^ ((lr & 7) << 3)));
        const size_t tbase =
            ((size_t)((b * 32 + c * 8 + ki) * 16 + 4 * w) << 9) + l * 8;
#pragma unroll
        for (int dbi = 0; dbi < 4; ++dbi) {
            bf16x8 vf = *(const bf16x8*)(VB + tbase + ((size_t)dbi << 9));
            acc2[dbi] = __builtin_amdgcn_mfma_f32_16x16x32_bf16(pf, vf, acc2[dbi], 0, 0, 0);
        }
    }
#pragma unroll
    for (int dbi = 0; dbi < 4; ++dbi)
#pragma unroll
        for (int r = 0; r < 4; ++r)
            Opart[((size_t)c * (BB * SS) + rowbase + lc * 4 + r) * DD
                  + 64 * w + 16 * dbi + lr] = acc2[dbi][r];
}

// ---------------------------------------------------------------------------
// Kernel 3: combine + output projection via MFMA, bf16 Wo (no in-loop cvt).
// grid = 128 qtiles x 4 col-quarters = 512 blocks.
// ---------------------------------------------------------------------------
__global__ __launch_bounds__(256, 2) void combine_mfma(
    const float* __restrict__ Opart, const float* __restrict__ esum,
    const unsigned short* __restrict__ Wob, const float* __restrict__ bo,
    float* __restrict__ out)
{
    __shared__ float inv_s[16];
    const int t = threadIdx.x;
    const int w = t >> 6, l = t & 63, lr = l & 15, lc = l >> 4;
    const int r0 = (blockIdx.x >> 2) * 16;   // global row
    const int ch = blockIdx.x & 3;           // col quarter

    if (t < 16) {
        float d = 0.f;
#pragma unroll
        for (int c = 0; c < NCH; ++c) d += esum[(size_t)c * (BB * SS) + r0 + t];
        inv_s[t] = 1.f / d;
    }
    __syncthreads();

    const float inv = inv_s[lr];
    bf16x8 af[8];
#pragma unroll
    for (int db = 0; db < 8; ++db) {
        const float* op = Opart + (size_t)(r0 + lr) * DD + db * 32 + 8 * lc;
        float s0 = 0.f, s1 = 0.f, s2 = 0.f, s3 = 0.f;
        float s4 = 0.f, s5 = 0.f, s6 = 0.f, s7 = 0.f;
#pragma unroll
        for (int c = 0; c < NCH; ++c) {
            const float* p = op + (size_t)c * ((size_t)BB * SS * DD);
            float4 a0 = *(const float4*)(p);
            float4 a1 = *(const float4*)(p + 4);
            s0 += a0.x; s1 += a0.y; s2 += a0.z; s3 += a0.w;
            s4 += a1.x; s5 += a1.y; s6 += a1.z; s7 += a1.w;
        }
        bf16x8 a;
        a[0] = (short)f2bf(s0 * inv); a[1] = (short)f2bf(s1 * inv);
        a[2] = (short)f2bf(s2 * inv); a[3] = (short)f2bf(s3 * inv);
        a[4] = (short)f2bf(s4 * inv); a[5] = (short)f2bf(s5 * inv);
        a[6] = (short)f2bf(s6 * inv); a[7] = (short)f2bf(s7 * inv);
        af[db] = a;
    }

    const int jb = 64 * ch + 16 * w;
    f32x4 acc = {0.f, 0.f, 0.f, 0.f};
#pragma unroll
    for (int db = 0; db < 8; ++db) {
        bf16x8 bf = *(const bf16x8*)(Wob + (size_t)(jb + lr) * DD + db * 32 + 8 * lc);
        acc = __builtin_amdgcn_mfma_f32_16x16x32_bf16(af[db], bf, acc, 0, 0, 0);
    }
    const float bov = bo[jb + lr];
#pragma unroll
    for (int r = 0; r < 4; ++r)
        out[(size_t)(r0 + lc * 4 + r) * DD + jb + lr] = acc[r] + bov;
}

// ---------------------------------------------------------------------------
extern "C" void kernel_launch(void* const* d_in, const int* in_sizes, int n_in,
                              void* d_out, int out_size, void* d_ws, size_t ws_size,
                              hipStream_t stream) {
    const float* x  = (const float*)d_in[0];
    const float* Wq = (const float*)d_in[1];
    const float* bq = (const float*)d_in[2];
    const float* Wk = (const float*)d_in[3];
    const float* bk = (const float*)d_in[4];
    const float* Wv = (const float*)d_in[5];
    const float* bv = (const float*)d_in[6];
    const float* Wo = (const float*)d_in[7];
    const float* bo = (const float*)d_in[8];
    float* out = (float*)d_out;

    // ws layout (bf16 first, then fp32):
    // Qb | Kb | VB | xb | Wqb | Wkb | Wvb | Wob || qq | kk | esum | Opart
    const size_t rows = (size_t)BB * SS;            // 2048
    unsigned short* Qb  = (unsigned short*)d_ws;
    unsigned short* Kb  = Qb + rows * DD;
    unsigned short* VB  = Kb + rows * DD;
    unsigned short* xb  = VB + rows * DD;
    unsigned short* Wqb = xb + rows * DD;
    unsigned short* Wkb = Wqb + (size_t)DD * DD;
    unsigned short* Wvb = Wkb + (size_t)DD * DD;
    unsigned short* Wob = Wvb + (size_t)DD * DD;
    float* qq    = (float*)(Wob + (size_t)DD * DD);
    float* kk    = qq + rows;
    float* esum  = kk + rows;
    float* Opart = esum + (size_t)NCH * rows;       // NCH*rows*DD floats

    cvt_bf16<<<384, 256, 0, stream>>>(x, Wq, Wk, Wv, Wo,
                                      xb, Wqb, Wkb, Wvb, Wob);
    qkv_mfma<<<(int)(rows / 16) * 3, 256, 0, stream>>>(
        xb, Wqb, bq, Wkb, bk, Wvb, bv, Qb, Kb, VB, qq, kk);
    attn_part_mfma<<<(int)(rows / 16) * NCH, 256, 0, stream>>>(
        Qb, Kb, VB, qq, kk, Opart, esum);
    combine_mfma<<<(int)(rows / 16) * 4, 256, 0, stream>>>(
        Opart, esum, Wob, bo, out);
}